// Round 1
// baseline (216.930 us; speedup 1.0000x reference)
//
#include <hip/hip_runtime.h>
#include <cstdint>
#include <cstddef>

using u16   = unsigned short;
using u16x4 = __attribute__((ext_vector_type(4))) unsigned short;
using u16x8 = __attribute__((ext_vector_type(8))) unsigned short;
using s16x8 = __attribute__((ext_vector_type(8))) short;
using f32x4 = __attribute__((ext_vector_type(4))) float;

#define B_DIM  2
#define S_DIM  2048
#define D_DIM  1024
#define H_DIM  16
#define DK_DIM 64

// round-to-nearest-even fp32 -> bf16 (bit pattern)
__device__ __forceinline__ u16 f2bf(float f) {
  union { float f; uint32_t u; } c; c.f = f;
  uint32_t u = c.u;
  return (u16)((u + 0x7FFFu + ((u >> 16) & 1u)) >> 16);
}

// async global->LDS, 16B per lane. LDS dest must be wave-uniform base (+lane*16 by HW).
__device__ __forceinline__ void gload16(const void* g, void* l) {
  __builtin_amdgcn_global_load_lds(
      (const __attribute__((address_space(1))) void*)g,
      (__attribute__((address_space(3))) void*)l, 16, 0, 0);
}

// ---------------------------------------------------------------------------
// fp32 -> bf16 cast, 8 elems/thread, up to 4 arrays selected by blockIdx.y
// ---------------------------------------------------------------------------
__global__ __launch_bounds__(256) void cast_bf16_kernel(
    const float* s0, const float* s1, const float* s2, const float* s3,
    u16* d0, u16* d1, u16* d2, u16* d3, int n)
{
  const float* s; u16* d;
  switch (blockIdx.y) {
    case 0: s = s0; d = d0; break;
    case 1: s = s1; d = d1; break;
    case 2: s = s2; d = d2; break;
    default: s = s3; d = d3; break;
  }
  int i = (blockIdx.x * 256 + threadIdx.x) * 8;
  if (i >= n) return;
  f32x4 a = *(const f32x4*)(s + i);
  f32x4 b = *(const f32x4*)(s + i + 4);
  u16x8 ov;
  ov[0] = f2bf(a[0]); ov[1] = f2bf(a[1]); ov[2] = f2bf(a[2]); ov[3] = f2bf(a[3]);
  ov[4] = f2bf(b[0]); ov[5] = f2bf(b[1]); ov[6] = f2bf(b[2]); ov[7] = f2bf(b[3]);
  *(u16x8*)(d + i) = ov;
}

// ---------------------------------------------------------------------------
// GEMM C[m,n] = sum_k A[m,k]*W[n,k] + bias[n]   (torch Linear, W row-major [N,K])
// BM=BN=128, BK=64, 256 threads (4 waves, 2x2), 16x16x32 bf16 MFMA.
// LDS tiles XOR-swizzled: logical byte L lives at L ^ ((row&7)<<4); staging keeps
// LDS linear and pre-swizzles the GLOBAL source (rule #21).
// mode 0: bf16 [M,1024] rowmajor; mode 1: bf16 vt[b][h][dk][s]; mode 2: fp32 rowmajor
// ---------------------------------------------------------------------------
#define BM 128
#define BN 128
#define BK 64

__device__ __forceinline__ void gemm_bt_core(
    const u16* __restrict__ A, const u16* __restrict__ W,
    const float* __restrict__ bias, void* __restrict__ out, int mode,
    int mtile, int ntile)
{
  __shared__ u16 Alds[BM * BK];
  __shared__ u16 Blds[BN * BK];
  const int K = 1024;
  const int tid = threadIdx.x;
  const int w = tid >> 6, l = tid & 63;
  const int lr = l & 15, lg = l >> 4;
  const int wr = w >> 1, wc = w & 1;
  const int m0 = mtile * BM, n0 = ntile * BN;

  f32x4 acc[4][4] = {};

  for (int kt = 0; kt < K / BK; ++kt) {
    const int k0 = kt * BK;
    #pragma unroll
    for (int i = 0; i < 4; ++i) {
      int c = i * 256 + tid;                 // 16B chunk id; 8 chunks per 128B row
      int r = c >> 3;
      int cb = ((c & 7) << 4) ^ ((r & 7) << 4);   // pre-swizzled source byte col
      gload16((const char*)(A + (size_t)(m0 + r) * K + k0) + cb,
              (char*)Alds + i * 4096 + w * 1024);
    }
    #pragma unroll
    for (int i = 0; i < 4; ++i) {
      int c = i * 256 + tid;
      int r = c >> 3;
      int cb = ((c & 7) << 4) ^ ((r & 7) << 4);
      gload16((const char*)(W + (size_t)(n0 + r) * K + k0) + cb,
              (char*)Blds + i * 4096 + w * 1024);
    }
    __syncthreads();
    #pragma unroll
    for (int ks = 0; ks < 2; ++ks) {
      s16x8 af[4], bf[4];
      #pragma unroll
      for (int mi = 0; mi < 4; ++mi) {
        int r = wr * 64 + mi * 16 + lr;
        int kb = (ks * 64 + lg * 16) ^ ((r & 7) << 4);
        af[mi] = *(const s16x8*)((const char*)Alds + r * 128 + kb);
      }
      #pragma unroll
      for (int ni = 0; ni < 4; ++ni) {
        int r = wc * 64 + ni * 16 + lr;
        int kb = (ks * 64 + lg * 16) ^ ((r & 7) << 4);
        bf[ni] = *(const s16x8*)((const char*)Blds + r * 128 + kb);
      }
      #pragma unroll
      for (int mi = 0; mi < 4; ++mi)
        #pragma unroll
        for (int ni = 0; ni < 4; ++ni)
          acc[mi][ni] = __builtin_amdgcn_mfma_f32_16x16x32_bf16(
              af[mi], bf[ni], acc[mi][ni], 0, 0, 0);
    }
    __syncthreads();
  }

  // epilogue: C row = (lane>>4)*4+reg, col = lane&15 within each 16x16 frag
  const int mbase = m0 + wr * 64 + lg * 4;
  const int nbase = n0 + wc * 64 + lr;
  #pragma unroll
  for (int ni = 0; ni < 4; ++ni) {
    int n = nbase + ni * 16;
    float bb = bias[n];
    #pragma unroll
    for (int mi = 0; mi < 4; ++mi) {
      int mr = mbase + mi * 16;
      f32x4 vv = acc[mi][ni];
      if (mode == 2) {
        float* o = (float*)out;
        #pragma unroll
        for (int r = 0; r < 4; ++r) o[(size_t)(mr + r) * 1024 + n] = vv[r] + bb;
      } else if (mode == 0) {
        u16* o = (u16*)out;
        #pragma unroll
        for (int r = 0; r < 4; ++r) o[(size_t)(mr + r) * 1024 + n] = f2bf(vv[r] + bb);
      } else {
        // vt[b][h][dk][s] : 4 consecutive s per lane -> one 8B store
        u16* o = (u16*)out;
        int b = mr >> 11, s = mr & (S_DIM - 1);
        int h = n >> 6, dk = n & 63;
        u16x4 pk;
        #pragma unroll
        for (int r = 0; r < 4; ++r) pk[r] = f2bf(vv[r] + bb);
        *(u16x4*)(o + ((size_t)((b * H_DIM + h) * DK_DIM + dk) * S_DIM + s)) = pk;
      }
    }
  }
}

__global__ __launch_bounds__(256) void qkv_gemm_kernel(
    const u16* xq, const u16* xk, const u16* xv,
    const u16* wq, const u16* wk, const u16* wv,
    const float* bq, const float* bk, const float* bv,
    u16* qlin, u16* klin, u16* vt)
{
  int z = blockIdx.z;
  const u16* A = (z == 0) ? xq : (z == 1) ? xk : xv;
  const u16* W = (z == 0) ? wq : (z == 1) ? wk : wv;
  const float* bias = (z == 0) ? bq : (z == 1) ? bk : bv;
  void* out = (z == 0) ? (void*)qlin : (z == 1) ? (void*)klin : (void*)vt;
  gemm_bt_core(A, W, bias, out, (z == 2) ? 1 : 0, blockIdx.y, blockIdx.x);
}

__global__ __launch_bounds__(256) void oproj_kernel(
    const u16* aout, const u16* wo, const float* bo, float* out)
{
  gemm_bt_core(aout, wo, bo, (void*)out, 2, blockIdx.y, blockIdx.x);
}

// ---------------------------------------------------------------------------
// Causal flash attention. Block = (qtile 64, h, b), 4 waves; wave owns 16 q-rows.
// Q in regs; K,V^T tiles (64x64 bf16) staged via global_load_lds with XOR swizzle;
// online softmax with 16-lane shfl reductions; P through per-wave swizzled LDS.
// ---------------------------------------------------------------------------
__global__ __launch_bounds__(256) void attn_kernel(
    const u16* __restrict__ qlin, const u16* __restrict__ klin,
    const u16* __restrict__ vt, u16* __restrict__ aout)
{
  __shared__ u16 Klds[64 * 64];
  __shared__ u16 Vlds[64 * 64];
  __shared__ u16 Plds[4][16 * 64];
  const int tid = threadIdx.x;
  const int w = tid >> 6, l = tid & 63;
  const int lr = l & 15, lg = l >> 4;
  const int qt = blockIdx.x, h = blockIdx.y, b = blockIdx.z;
  const int q0 = qt * 64;

  // Q fragments for this wave's 16 rows (A-frag: row=lane&15, k=(lane>>4)*8+i)
  const u16* qrow = qlin + (size_t)(b * S_DIM + q0 + w * 16 + lr) * D_DIM + h * DK_DIM;
  s16x8 aq[2];
  aq[0] = *(const s16x8*)(qrow + lg * 8);
  aq[1] = *(const s16x8*)(qrow + 32 + lg * 8);

  const u16* kbase = klin + (size_t)b * S_DIM * D_DIM + h * DK_DIM;   // + j*D
  const u16* vbase = vt + (size_t)(b * H_DIM + h) * DK_DIM * S_DIM;   // + dk*S + s

  f32x4 o[4] = {};
  float m_run[4], l_run[4];
  int sq[4];
  #pragma unroll
  for (int r = 0; r < 4; ++r) {
    m_run[r] = -1e30f; l_run[r] = 0.f;
    sq[r] = q0 + w * 16 + lg * 4 + r;
  }

  for (int jt = 0; jt <= qt; ++jt) {
    const int j0 = jt * 64;
    #pragma unroll
    for (int i = 0; i < 2; ++i) {           // K tile: rows j (stride D in global)
      int c = i * 256 + tid;
      int r = c >> 3;
      int cb = ((c & 7) << 4) ^ ((r & 7) << 4);
      gload16((const char*)(kbase + (size_t)(j0 + r) * D_DIM) + cb,
              (char*)Klds + i * 4096 + w * 1024);
    }
    #pragma unroll
    for (int i = 0; i < 2; ++i) {           // V^T tile: rows dk (stride S in global)
      int c = i * 256 + tid;
      int r = c >> 3;
      int cb = ((c & 7) << 4) ^ ((r & 7) << 4);
      gload16((const char*)(vbase + (size_t)r * S_DIM + j0) + cb,
              (char*)Vlds + i * 4096 + w * 1024);
    }
    __syncthreads();

    // S = Q K^T (gemm_bt form: B-frag reads K rows)
    f32x4 s4[4] = {};
    #pragma unroll
    for (int ks = 0; ks < 2; ++ks) {
      s16x8 bk4[4];
      #pragma unroll
      for (int ni = 0; ni < 4; ++ni) {
        int j = ni * 16 + lr;
        int kb = (ks * 64 + lg * 16) ^ ((j & 7) << 4);
        bk4[ni] = *(const s16x8*)((const char*)Klds + j * 128 + kb);
      }
      #pragma unroll
      for (int ni = 0; ni < 4; ++ni)
        s4[ni] = __builtin_amdgcn_mfma_f32_16x16x32_bf16(aq[ks], bk4[ni], s4[ni], 0, 0, 0);
    }

    // online softmax (rows r = lg*4+reg; cols spread over 16 lanes x 4 frags)
    #pragma unroll
    for (int reg = 0; reg < 4; ++reg) {
      float mx = -1e30f;
      #pragma unroll
      for (int ni = 0; ni < 4; ++ni) {
        float vsc = s4[ni][reg] * 0.125f;            // 1/sqrt(DK)
        if (j0 + ni * 16 + lr > sq[reg]) vsc = -1e30f;  // causal mask
        s4[ni][reg] = vsc;
        mx = fmaxf(mx, vsc);
      }
      #pragma unroll
      for (int off = 1; off < 16; off <<= 1) mx = fmaxf(mx, __shfl_xor(mx, off));
      float mnew = fmaxf(m_run[reg], mx);
      float corr = __expf(m_run[reg] - mnew);
      float ps = 0.f;
      #pragma unroll
      for (int ni = 0; ni < 4; ++ni) {
        float pv = __expf(s4[ni][reg] - mnew);
        s4[ni][reg] = pv;
        ps += pv;
      }
      #pragma unroll
      for (int off = 1; off < 16; off <<= 1) ps += __shfl_xor(ps, off);
      l_run[reg] = l_run[reg] * corr + ps;
      m_run[reg] = mnew;
      #pragma unroll
      for (int ni = 0; ni < 4; ++ni) o[ni][reg] *= corr;
    }

    // P: C-layout -> A-frag layout via per-wave swizzled LDS buffer
    u16* pw = &Plds[w][0];
    #pragma unroll
    for (int ni = 0; ni < 4; ++ni)
      #pragma unroll
      for (int reg = 0; reg < 4; ++reg) {
        int r = lg * 4 + reg;
        int cb = ((ni * 16 + lr) * 2) ^ ((r & 7) << 4);
        *(u16*)((char*)pw + r * 128 + cb) = f2bf(s4[ni][reg]);
      }
    asm volatile("s_waitcnt lgkmcnt(0)" ::: "memory");  // wave-internal LDS ordering
    s16x8 pa[2];
    #pragma unroll
    for (int ks = 0; ks < 2; ++ks) {
      int kb = (ks * 64 + lg * 16) ^ ((lr & 7) << 4);
      pa[ks] = *(const s16x8*)((const char*)pw + lr * 128 + kb);
    }

    // O += P V   (B-frag reads V^T rows: col=dk, k=j)
    #pragma unroll
    for (int ks = 0; ks < 2; ++ks) {
      s16x8 bv4[4];
      #pragma unroll
      for (int ni = 0; ni < 4; ++ni) {
        int dk = ni * 16 + lr;
        int jb = (ks * 64 + lg * 16) ^ ((dk & 7) << 4);
        bv4[ni] = *(const s16x8*)((const char*)Vlds + dk * 128 + jb);
      }
      #pragma unroll
      for (int ni = 0; ni < 4; ++ni)
        o[ni] = __builtin_amdgcn_mfma_f32_16x16x32_bf16(pa[ks], bv4[ni], o[ni], 0, 0, 0);
    }
    __syncthreads();
  }

  #pragma unroll
  for (int reg = 0; reg < 4; ++reg) {
    float inv = 1.f / l_run[reg];
    #pragma unroll
    for (int ni = 0; ni < 4; ++ni)
      aout[(size_t)(b * S_DIM + sq[reg]) * D_DIM + h * DK_DIM + ni * 16 + lr] =
          f2bf(o[ni][reg] * inv);
  }
}

// ---------------------------------------------------------------------------
extern "C" void kernel_launch(void* const* d_in, const int* in_sizes, int n_in,
                              void* d_out, int out_size, void* d_ws, size_t ws_size,
                              hipStream_t stream)
{
  (void)in_sizes; (void)n_in; (void)out_size; (void)ws_size;
  const float* q  = (const float*)d_in[0];
  const float* k  = (const float*)d_in[1];
  const float* v  = (const float*)d_in[2];
  // d_in[3] = mask (causal tril) — structure hardcoded in attn_kernel
  const float* Wq = (const float*)d_in[4];
  const float* bq = (const float*)d_in[5];
  const float* Wk = (const float*)d_in[6];
  const float* bk = (const float*)d_in[7];
  const float* Wv = (const float*)d_in[8];
  const float* bv = (const float*)d_in[9];
  const float* Wo = (const float*)d_in[10];
  const float* bo = (const float*)d_in[11];
  float* out = (float*)d_out;

  const size_t XSZ = (size_t)B_DIM * S_DIM * D_DIM;   // 4,194,304
  const size_t WSZ = (size_t)D_DIM * D_DIM;           // 1,048,576

  u16* p = (u16*)d_ws;
  u16* qbf  = p; p += XSZ;
  u16* kbf  = p; p += XSZ;
  u16* vbf  = p; p += XSZ;
  u16* wqb  = p; p += WSZ;
  u16* wkb  = p; p += WSZ;
  u16* wvb  = p; p += WSZ;
  u16* wob  = p; p += WSZ;
  u16* qlin = p; p += XSZ;   // Q proj, [B*S, D] bf16
  u16* klin = p; p += XSZ;   // K proj, [B*S, D] bf16
  u16* vtb  = p; p += XSZ;   // V proj, [B,H,DK,S] bf16 (transposed)
  u16* aoutb = p; p += XSZ;  // attention out, [B*S, D] bf16

  cast_bf16_kernel<<<dim3((unsigned)(XSZ / 8 / 256), 3), 256, 0, stream>>>(
      q, k, v, nullptr, qbf, kbf, vbf, nullptr, (int)XSZ);
  cast_bf16_kernel<<<dim3((unsigned)(WSZ / 8 / 256), 4), 256, 0, stream>>>(
      Wq, Wk, Wv, Wo, wqb, wkb, wvb, wob, (int)WSZ);
  qkv_gemm_kernel<<<dim3(8, 32, 3), 256, 0, stream>>>(
      qbf, kbf, vbf, wqb, wkb, wvb, bq, bk, bv, qlin, klin, vtb);
  attn_kernel<<<dim3(32, 16, 2), 256, 0, stream>>>(qlin, klin, vtb, aoutb);
  oproj_kernel<<<dim3(8, 32), 256, 0, stream>>>(aoutb, wob, bo, out);
}